// Round 7
// baseline (877.141 us; speedup 1.0000x reference)
//
#include <hip/hip_runtime.h>
#include <stdint.h>

#define T_TOK 8192
#define DIM   1024
#define NE    8
#define NH    2816
#define NROWS (T_TOK*2)

typedef __attribute__((ext_vector_type(8))) __bf16 bf16x8;
typedef __attribute__((ext_vector_type(4))) float  f32x4;

typedef __attribute__((address_space(1))) const unsigned int g_as1;
typedef __attribute__((address_space(3))) unsigned int l_as3;
#define GLL(g, l) __builtin_amdgcn_global_load_lds((g_as1*)(g), (l_as3*)(l), 16, 0, 0)
#define MFMA16(a,b,c) __builtin_amdgcn_mfma_f32_16x16x32_bf16(a,b,c,0,0,0)

__device__ __forceinline__ unsigned short f2bf(float f){
  union { float f; uint32_t u; } v; v.f = f;
  uint32_t r = (v.u + 0x7FFFu + ((v.u >> 16) & 1u)) >> 16;
  return (unsigned short)r;
}

// ---------------- init / zero / convert ----------------

__global__ void init_k(int* counts, int* cursor){
  int i = threadIdx.x;
  if (i < NE){ counts[i] = 0; cursor[i] = 0; }
}

__global__ void zero_out_k(float4* __restrict__ out){
  int i = blockIdx.x*blockDim.x + threadIdx.x;
  const int n4 = T_TOK*DIM/4;
  const float4 z = make_float4(0.f,0.f,0.f,0.f);
  for (; i < n4; i += gridDim.x*blockDim.x) out[i] = z;
}

__global__ void cvt_k(const float* __restrict__ x, unsigned short* __restrict__ xbf){
  int i = blockIdx.x*blockDim.x + threadIdx.x;
  const int total = T_TOK*DIM/8;
  for (; i < total; i += gridDim.x*blockDim.x){
    const float4 a = *(const float4*)(x + (size_t)i*8);
    const float4 b = *(const float4*)(x + (size_t)i*8 + 4);
    ushort4 lo = make_ushort4(f2bf(a.x), f2bf(a.y), f2bf(a.z), f2bf(a.w));
    ushort4 hi = make_ushort4(f2bf(b.x), f2bf(b.y), f2bf(b.z), f2bf(b.w));
    *(ushort4*)(xbf + (size_t)i*8)     = lo;
    *(ushort4*)(xbf + (size_t)i*8 + 4) = hi;
  }
}

// transpose-convert: f32 [R][C] -> bf16 [C][R]
__global__ __launch_bounds__(256) void transp_k(const float* __restrict__ in,
    unsigned short* __restrict__ outp, int R, int C)
{
  __shared__ unsigned short Tl[64*68];
  const int r0 = blockIdx.x*64, c0 = blockIdx.y*64;
  const size_t mbase = (size_t)blockIdx.z * (size_t)R * (size_t)C;
  const float* ip = in + mbase;
  unsigned short* op = outp + mbase;
  const int t = threadIdx.x;
  #pragma unroll
  for (int i=0;i<4;i++){
    const int r  = (t>>4) + i*16;
    const int cq = t & 15;
    const float4 v = *(const float4*)(ip + (size_t)(r0+r)*C + c0 + cq*4);
    Tl[(cq*4+0)*68 + r] = f2bf(v.x);
    Tl[(cq*4+1)*68 + r] = f2bf(v.y);
    Tl[(cq*4+2)*68 + r] = f2bf(v.z);
    Tl[(cq*4+3)*68 + r] = f2bf(v.w);
  }
  __syncthreads();
  #pragma unroll
  for (int i=0;i<4;i++){
    const int idx = i*1024 + t*4;
    const int c = idx>>6, r = idx&63;
    const ushort4 v = *(const ushort4*)&Tl[c*68 + r];
    *(ushort4*)(op + (size_t)(c0+c)*R + r0 + r) = v;
  }
}

// fused w1+w3 transpose: z in [0,2*NE)
__global__ __launch_bounds__(256) void transp2_k(const float* __restrict__ w1,
    const float* __restrict__ w3, unsigned short* __restrict__ w1t,
    unsigned short* __restrict__ w3t)
{
  __shared__ unsigned short Tl[64*68];
  const int r0 = blockIdx.x*64, c0 = blockIdx.y*64;
  const int z = blockIdx.z;
  const size_t mbase = (size_t)(z & (NE-1)) * (size_t)DIM * (size_t)NH;
  const float* ip = (z < NE ? w1 : w3) + mbase;
  unsigned short* op = (z < NE ? w1t : w3t) + mbase;
  const int t = threadIdx.x;
  #pragma unroll
  for (int i=0;i<4;i++){
    const int r  = (t>>4) + i*16;
    const int cq = t & 15;
    const float4 v = *(const float4*)(ip + (size_t)(r0+r)*NH + c0 + cq*4);
    Tl[(cq*4+0)*68 + r] = f2bf(v.x);
    Tl[(cq*4+1)*68 + r] = f2bf(v.y);
    Tl[(cq*4+2)*68 + r] = f2bf(v.z);
    Tl[(cq*4+3)*68 + r] = f2bf(v.w);
  }
  __syncthreads();
  #pragma unroll
  for (int i=0;i<4;i++){
    const int idx = i*1024 + t*4;
    const int c = idx>>6, r = idx&63;
    const ushort4 v = *(const ushort4*)&Tl[c*68 + r];
    *(ushort4*)(op + (size_t)(c0+c)*DIM + r0 + r) = v;
  }
}

// ---------------- router ----------------

__global__ void router_k(const float* __restrict__ x, const float* __restrict__ rw,
                         int* __restrict__ topk_e, float* __restrict__ topk_w,
                         int* __restrict__ counts){
  const int t = blockIdx.x;
  const int l = threadIdx.x;
  const float* xr = x + (size_t)t * DIM;
  float acc[NE];
  #pragma unroll
  for (int e=0;e<NE;e++) acc[e] = 0.f;
  #pragma unroll
  for (int i=0;i<DIM/64;i++){
    float xv = xr[l + 64*i];
    #pragma unroll
    for (int e=0;e<NE;e++) acc[e] += xv * rw[e*DIM + l + 64*i];
  }
  #pragma unroll
  for (int e=0;e<NE;e++){
    float v = acc[e];
    #pragma unroll
    for (int off=32; off; off>>=1) v += __shfl_xor(v, off);
    acc[e] = v;
  }
  if (l == 0){
    int e0 = 0; float v0 = acc[0];
    #pragma unroll
    for (int e=1;e<NE;e++) if (acc[e] > v0){ v0 = acc[e]; e0 = e; }
    int e1 = -1; float v1 = -1e30f;
    #pragma unroll
    for (int e=0;e<NE;e++) if (e != e0 && acc[e] > v1){ v1 = acc[e]; e1 = e; }
    float ex = __expf(v1 - v0);
    float s  = 1.f + ex;
    topk_e[t*2]   = e0;  topk_e[t*2+1] = e1;
    topk_w[t*2]   = 1.f/s; topk_w[t*2+1] = ex/s;
    atomicAdd(&counts[e0], 1);
    atomicAdd(&counts[e1], 1);
  }
}

__global__ void prefix_k(const int* __restrict__ counts, int* __restrict__ offs){
  if (threadIdx.x == 0 && blockIdx.x == 0){
    int s = 0;
    for (int e=0;e<NE;e++){ offs[e] = s; s += counts[e]; }
  }
}

__global__ void scatter_k(const int* __restrict__ topk_e, const float* __restrict__ topk_w,
                          const int* __restrict__ offs, int* __restrict__ cursor,
                          int* __restrict__ row_tok, float* __restrict__ row_w){
  int t = blockIdx.x*blockDim.x + threadIdx.x;
  if (t >= T_TOK) return;
  #pragma unroll
  for (int k=0;k<2;k++){
    int e = topk_e[t*2+k];
    int p = atomicAdd(&cursor[e], 1);
    int flat = offs[e] + p;
    row_tok[flat] = t;
    row_w[flat]   = topk_w[t*2+k];
  }
}

// ============ 8-phase-style big-tile GEMMs (T3+T4+T2+T5) ============
// BM=256, BK=64, 8 waves (2Mx4N), dbuf LDS 128KB, 4 phases per K-tile.
// Stage units (16KB = 2 GLL/thread each) for tile kt+1 during kt's phases:
//   slot0@p0, slot1@p1, slot2@p2(A rows {0-63,128-191}), slot3@p3(A rows {64-127,192-255}).
// Need-by: p0/p1 read B(all)+A-even units; p2/p3 read A-odd units.
// Waits: end-p1 vmcnt(4) retires A-odd(kt); end-p3 vmcnt(2) retires slots0-2(kt+1).
// Swizzle: 16B chunk ^= (row&7) on GLL source and ds_read (both sides).

// GEMM1: h = silu(X@W1)*(X@W3). BN=128 per matrix.
__global__ __launch_bounds__(512,2) void gemm1_8p(
    const unsigned short* __restrict__ xbf,
    const unsigned short* __restrict__ w1t, const unsigned short* __restrict__ w3t,
    unsigned short* __restrict__ hbuf,
    const int* __restrict__ row_tok,
    const int* __restrict__ counts, const int* __restrict__ offs)
{
  __shared__ unsigned short As [2][256*64];   // 64 KB
  __shared__ unsigned short B1s[2][128*64];   // 32 KB
  __shared__ unsigned short B3s[2][128*64];   // 32 KB

  // locality grid: lids (e, h-tile, rb), chunk 1408 = one expert per XCD
  const int i   = blockIdx.y*64 + blockIdx.x;      // grid (64,176)
  const int lid = (i & 7)*1408 + (i >> 3);
  const int e   = lid / 1408;
  const int rem = lid - e*1408;
  const int h0  = (rem >> 6) * 128;                // 22 h-tiles
  const int rb  = rem & 63;

  const int cnt  = counts[e];
  const int row0 = rb * 256;
  if (row0 >= cnt) return;
  const int nv   = min(256, cnt - row0);
  const int base = offs[e] + row0;
  const int NK   = DIM/64;                         // 16

  const int t  = threadIdx.x;
  const int r8 = t >> 3, sl = t & 7;
  const int csw = ((sl ^ (r8 & 7)) << 3);          // swizzled src chunk (shorts)
  const int tk0 = row_tok[base + min(r8,       nv-1)];
  const int tk1 = row_tok[base + min(r8 + 64,  nv-1)];
  const int tk2 = row_tok[base + min(r8 + 128, nv-1)];
  const int tk3 = row_tok[base + min(r8 + 192, nv-1)];
  const unsigned short* aP0 = xbf + (size_t)tk0*DIM + csw;
  const unsigned short* aP1 = xbf + (size_t)tk1*DIM + csw;
  const unsigned short* aP2 = xbf + (size_t)tk2*DIM + csw;
  const unsigned short* aP3 = xbf + (size_t)tk3*DIM + csw;
  const unsigned short* b1P0 = w1t + ((size_t)(e*NH + h0) + r8)*DIM + csw;
  const unsigned short* b1P1 = b1P0 + (size_t)64*DIM;
  const unsigned short* b3P0 = w3t + ((size_t)(e*NH + h0) + r8)*DIM + csw;
  const unsigned short* b3P1 = b3P0 + (size_t)64*DIM;
  const int lo = t*16;

  const int wid = t >> 6, l = t & 63;
  const int wr = wid >> 2, wc = wid & 3;           // 2M x 4N waves
  const int lr = l & 15,  lk = l >> 4;

  f32x4 acc1[8][2], acc3[8][2];
  #pragma unroll
  for (int m=0;m<8;m++)
    #pragma unroll
    for (int n=0;n<2;n++){ acc1[m][n] = (f32x4)0.f; acc3[m][n] = (f32x4)0.f; }

  // prologue: stage tile0, slots 0..3 in steady-state order
  GLL(b1P0, (char*)B1s[0] + lo);          GLL(b1P1, (char*)B1s[0] + 8192 + lo);
  GLL(b3P0, (char*)B3s[0] + lo);          GLL(b3P1, (char*)B3s[0] + 8192 + lo);
  GLL(aP0,  (char*)As[0]  + lo);          GLL(aP2,  (char*)As[0]  + 16384 + lo);
  GLL(aP1,  (char*)As[0]  + 8192 + lo);   GLL(aP3,  (char*)As[0]  + 24576 + lo);
  asm volatile("s_waitcnt vmcnt(2)" ::: "memory");
  __builtin_amdgcn_s_barrier();

  for (int kt=0; kt<NK; ++kt){
    const int cur = kt & 1;
    const int kof = (kt+1)*64;
    const unsigned short* Ab  = As [cur];
    const unsigned short* B1b = B1s[cur];
    const unsigned short* B3b = B3s[cur];
    char* Ad  = (char*)As [cur^1];
    char* B1d = (char*)B1s[cur^1];
    char* B3d = (char*)B3s[cur^1];
    const bool st = (kt+1 < NK);

    bf16x8 b1f[2][2], b3f[2][2];
    #pragma unroll
    for (int p=0; p<4; ++p){
      // ds-load this phase's A frags (m-pair p)
      bf16x8 a[2][2];
      #pragma unroll
      for (int j=0;j<2;j++){
        const int row = wr*128 + (p*2+j)*16 + lr;
        #pragma unroll
        for (int ks=0;ks<2;ks++){
          const int ck = ks*4 + lk;
          a[j][ks] = *(const bf16x8*)&Ab[row*64 + ((ck ^ (row & 7)) << 3)];
        }
      }
      if (p==0){
        #pragma unroll
        for (int n=0;n<2;n++){
          const int brow = wc*32 + n*16 + lr;
          #pragma unroll
          for (int ks=0;ks<2;ks++){
            const int ck = ks*4 + lk;
            const int boff = brow*64 + ((ck ^ (brow & 7)) << 3);
            b1f[n][ks] = *(const bf16x8*)&B1b[boff];
            b3f[n][ks] = *(const bf16x8*)&B3b[boff];
          }
        }
      }
      // stage one unit of tile kt+1
      if (st){
        if      (p==0){ GLL(b1P0+kof, B1d+lo);      GLL(b1P1+kof, B1d+8192+lo); }
        else if (p==1){ GLL(b3P0+kof, B3d+lo);      GLL(b3P1+kof, B3d+8192+lo); }
        else if (p==2){ GLL(aP0+kof,  Ad+lo);       GLL(aP2+kof,  Ad+16384+lo); }
        else          { GLL(aP1+kof,  Ad+8192+lo);  GLL(aP3+kof,  Ad+24576+lo); }
      }
      // counted waits (T4)
      if (p==1){ if (st) asm volatile("s_waitcnt vmcnt(4)" ::: "memory");
                 else    asm volatile("s_waitcnt vmcnt(0)" ::: "memory"); }
      if (p==3){ asm volatile("s_waitcnt vmcnt(2)" ::: "memory"); }
      __builtin_amdgcn_s_barrier();
      asm volatile("s_waitcnt lgkmcnt(0)" ::: "memory");
      __builtin_amdgcn_s_setprio(1);
      #pragma unroll
      for (int j=0;j<2;j++)
        #pragma unroll
        for (int ks=0;ks<2;ks++)
          #pragma unroll
          for (int n=0;n<2;n++){
            acc1[p*2+j][n] = MFMA16(a[j][ks], b1f[n][ks], acc1[p*2+j][n]);
            acc3[p*2+j][n] = MFMA16(a[j][ks], b3f[n][ks], acc3[p*2+j][n]);
          }
      __builtin_amdgcn_s_setprio(0);
      __builtin_amdgcn_s_barrier();
    }
  }

  // epilogue: SwiGLU, bf16 store
  #pragma unroll
  for (int m=0;m<8;m++){
    #pragma unroll
    for (int i2=0;i2<4;i2++){
      const int r = wr*128 + m*16 + lk*4 + i2;
      if (r < nv){
        const size_t rowbase = (size_t)(base + r) * NH;
        #pragma unroll
        for (int n=0;n<2;n++){
          float z  = acc1[m][n][i2];
          float p3 = acc3[m][n][i2];
          float hv = (z / (1.f + __expf(-z))) * p3;
          hbuf[rowbase + h0 + wc*32 + n*16 + lr] = f2bf(hv);
        }
      }
    }
  }
}

// GEMM2: out += rw*(H@W2). BM=256, BN=256, K=2816.
__global__ __launch_bounds__(512,2) void gemm2_8p(
    const unsigned short* __restrict__ hbuf,
    const unsigned short* __restrict__ w2t,
    float* __restrict__ out,
    const int* __restrict__ row_tok, const float* __restrict__ row_w,
    const int* __restrict__ counts, const int* __restrict__ offs)
{
  __shared__ unsigned short As[2][256*64];   // 64 KB
  __shared__ unsigned short Bs[2][256*64];   // 64 KB

  // locality grid: lids (e, d-tile, rb), chunk 256 = one expert per XCD
  const int i   = blockIdx.y*64 + blockIdx.x;      // grid (64,32)
  const int lid = (i & 7)*256 + (i >> 3);
  const int e   = lid >> 8;
  const int rem = lid & 255;
  const int d0  = (rem >> 6) * 256;                // 4 d-tiles
  const int rb  = rem & 63;

  const int cnt  = counts[e];
  const int row0 = rb * 256;
  if (row0 >= cnt) return;
  const int nv   = min(256, cnt - row0);
  const int base = offs[e] + row0;
  const int NK   = NH/64;                          // 44

  const int t  = threadIdx.x;
  const int r8 = t >> 3, sl = t & 7;
  const int csw = ((sl ^ (r8 & 7)) << 3);
  const unsigned short* aP0 = hbuf + (size_t)(base + min(r8,       nv-1))*NH + csw;
  const unsigned short* aP1 = hbuf + (size_t)(base + min(r8 + 64,  nv-1))*NH + csw;
  const unsigned short* aP2 = hbuf + (size_t)(base + min(r8 + 128, nv-1))*NH + csw;
  const unsigned short* aP3 = hbuf + (size_t)(base + min(r8 + 192, nv-1))*NH + csw;
  const unsigned short* bP0 = w2t + ((size_t)(e*DIM + d0) + r8)*NH + csw;
  const unsigned short* bP1 = bP0 + (size_t)64*NH;
  const unsigned short* bP2 = bP0 + (size_t)128*NH;
  const unsigned short* bP3 = bP0 + (size_t)192*NH;
  const int lo = t*16;

  const int wid = t >> 6, l = t & 63;
  const int wr = wid >> 2, wc = wid & 3;
  const int lr = l & 15,  lk = l >> 4;

  f32x4 acc[8][4];
  #pragma unroll
  for (int m=0;m<8;m++)
    #pragma unroll
    for (int n=0;n<4;n++) acc[m][n] = (f32x4)0.f;

  // prologue: slots 0..3
  GLL(bP0, (char*)Bs[0] + lo);          GLL(bP1, (char*)Bs[0] + 8192 + lo);
  GLL(bP2, (char*)Bs[0] + 16384 + lo);  GLL(bP3, (char*)Bs[0] + 24576 + lo);
  GLL(aP0, (char*)As[0] + lo);          GLL(aP2, (char*)As[0] + 16384 + lo);
  GLL(aP1, (char*)As[0] + 8192 + lo);   GLL(aP3, (char*)As[0] + 24576 + lo);
  asm volatile("s_waitcnt vmcnt(2)" ::: "memory");
  __builtin_amdgcn_s_barrier();

  for (int kt=0; kt<NK; ++kt){
    const int cur = kt & 1;
    const int kof = (kt+1)*64;
    const unsigned short* Ab = As[cur];
    const unsigned short* Bb = Bs[cur];
    char* Ad = (char*)As[cur^1];
    char* Bd = (char*)Bs[cur^1];
    const bool st = (kt+1 < NK);

    bf16x8 bf[4][2];
    #pragma unroll
    for (int p=0; p<4; ++p){
      bf16x8 a[2][2];
      #pragma unroll
      for (int j=0;j<2;j++){
        const int row = wr*128 + (p*2+j)*16 + lr;
        #pragma unroll
        for (int ks=0;ks<2;ks++){
          const int ck = ks*4 + lk;
          a[j][ks] = *(const bf16x8*)&Ab[row*64 + ((ck ^ (row & 7)) << 3)];
        }
      }
      if (p==0){
        #pragma unroll
        for (int n=0;n<4;n++){
          const int brow = wc*64 + n*16 + lr;
          #pragma unroll
          for (int ks=0;ks<2;ks++){
            const int ck = ks*4 + lk;
            bf[n][ks] = *(const bf16x8*)&Bb[brow*64 + ((ck ^ (brow & 7)) << 3)];
          }
        }
      }
      if (st){
        if      (p==0){ GLL(bP0+kof, Bd+lo);        GLL(bP1+kof, Bd+8192+lo); }
        else if (p==1){ GLL(bP2+kof, Bd+16384+lo);  GLL(bP3+kof, Bd+24576+lo); }
        else if (p==2){ GLL(aP0+kof, Ad+lo);        GLL(aP2+kof, Ad+16384+lo); }
        else          { GLL(aP1+kof, Ad+8192+lo);   GLL(aP3+kof, Ad+24576+lo); }
      }
      if (p==1){ if (st) asm volatile("s_waitcnt vmcnt(4)" ::: "memory");
                 else    asm volatile("s_waitcnt vmcnt(0)" ::: "memory"); }
      if (p==3){ asm volatile("s_waitcnt vmcnt(2)" ::: "memory"); }
      __builtin_amdgcn_s_barrier();
      asm volatile("s_waitcnt lgkmcnt(0)" ::: "memory");
      __builtin_amdgcn_s_setprio(1);
      #pragma unroll
      for (int j=0;j<2;j++)
        #pragma unroll
        for (int ks=0;ks<2;ks++)
          #pragma unroll
          for (int n=0;n<4;n++)
            acc[p*2+j][n] = MFMA16(a[j][ks], bf[n][ks], acc[p*2+j][n]);
      __builtin_amdgcn_s_setprio(0);
      __builtin_amdgcn_s_barrier();
    }
  }

  #pragma unroll
  for (int m=0;m<8;m++){
    #pragma unroll
    for (int i2=0;i2<4;i2++){
      const int r = wr*128 + m*16 + lk*4 + i2;
      if (r < nv){
        const int flat = base + r;
        const int tok  = row_tok[flat];
        const float wgt = row_w[flat];
        float* orow = out + (size_t)tok * DIM + d0 + wc*64;
        #pragma unroll
        for (int n=0;n<4;n++)
          atomicAdd(&orow[n*16 + lr], acc[m][n][i2] * wgt);
      }
    }
  }
}

// ============ SLOW FALLBACK (f32 weights, small ws) ============

__global__ __launch_bounds__(256) void gemm1_k(
    const unsigned short* __restrict__ xbf,
    const float* __restrict__ w1, const float* __restrict__ w3,
    unsigned short* __restrict__ hbuf,
    const int* __restrict__ row_tok,
    const int* __restrict__ counts, const int* __restrict__ offs)
{
  __shared__ unsigned short Al [128*32];
  __shared__ unsigned short B1l[128*32];
  __shared__ unsigned short B3l[128*32];
  const int e   = blockIdx.y >> 6;
  const int rb  = blockIdx.y & 63;
  const int cnt = counts[e];
  const int row0 = rb * 128;
  if (row0 >= cnt) return;
  const int nv   = min(128, cnt - row0);
  const int base = offs[e] + row0;
  const int h0   = blockIdx.x * 128;
  const int t  = threadIdx.x;
  const int ar0 = t >> 2;
  const int ac  = t & 3;
  const int tok0 = row_tok[base + min(ar0,      nv-1)];
  const int tok1 = row_tok[base + min(ar0 + 64, nv-1)];
  const size_t asrc0 = (size_t)tok0 * DIM + ac*8;
  const size_t asrc1 = (size_t)tok1 * DIM + ac*8;
  const int dg = t >> 5;
  const int hq = t & 31;
  const float* w1p = w1 + (size_t)e * DIM * NH + (size_t)(h0 + hq*4);
  const float* w3p = w3 + (size_t)e * DIM * NH + (size_t)(h0 + hq*4);
  const int wid = t >> 6, l = t & 63;
  const int wr = wid >> 1, wc = wid & 1;
  const int lr = l & 15,  lk = l >> 4;
  f32x4 acc1[4][4], acc3[4][4];
  #pragma unroll
  for (int m=0;m<4;m++)
    #pragma unroll
    for (int n=0;n<4;n++){ acc1[m][n] = (f32x4)0.f; acc3[m][n] = (f32x4)0.f; }
  for (int kk=0; kk<DIM/32; ++kk){
    const int k0 = kk*32;
    __syncthreads();
    *(uint4*)&Al[ar0*32 + ac*8]      = *(const uint4*)(xbf + asrc0 + k0);
    *(uint4*)&Al[(ar0+64)*32 + ac*8] = *(const uint4*)(xbf + asrc1 + k0);
    {
      const float4 f0 = *(const float4*)(w1p + (size_t)(k0 + dg*4 + 0)*NH);
      const float4 f1 = *(const float4*)(w1p + (size_t)(k0 + dg*4 + 1)*NH);
      const float4 f2 = *(const float4*)(w1p + (size_t)(k0 + dg*4 + 2)*NH);
      const float4 f3 = *(const float4*)(w1p + (size_t)(k0 + dg*4 + 3)*NH);
      const float* p0=(const float*)&f0; const float* p1=(const float*)&f1;
      const float* p2=(const float*)&f2; const float* p3=(const float*)&f3;
      #pragma unroll
      for (int j=0;j<4;j++){
        ushort4 pk = make_ushort4(f2bf(p0[j]), f2bf(p1[j]), f2bf(p2[j]), f2bf(p3[j]));
        *(ushort4*)&B1l[(hq*4+j)*32 + dg*4] = pk;
      }
      const float4 g0 = *(const float4*)(w3p + (size_t)(k0 + dg*4 + 0)*NH);
      const float4 g1 = *(const float4*)(w3p + (size_t)(k0 + dg*4 + 1)*NH);
      const float4 g2 = *(const float4*)(w3p + (size_t)(k0 + dg*4 + 2)*NH);
      const float4 g3 = *(const float4*)(w3p + (size_t)(k0 + dg*4 + 3)*NH);
      const float* q0=(const float*)&g0; const float* q1=(const float*)&g1;
      const float* q2=(const float*)&g2; const float* q3=(const float*)&g3;
      #pragma unroll
      for (int j=0;j<4;j++){
        ushort4 pk = make_ushort4(f2bf(q0[j]), f2bf(q1[j]), f2bf(q2[j]), f2bf(q3[j]));
        *(ushort4*)&B3l[(hq*4+j)*32 + dg*4] = pk;
      }
    }
    __syncthreads();
    bf16x8 a[4], b1[4], b3[4];
    #pragma unroll
    for (int m=0;m<4;m++) a[m] = *(const bf16x8*)&Al[(wr*64 + m*16 + lr)*32 + lk*8];
    #pragma unroll
    for (int n=0;n<4;n++){
      b1[n] = *(const bf16x8*)&B1l[(wc*64 + n*16 + lr)*32 + lk*8];
      b3[n] = *(const bf16x8*)&B3l[(wc*64 + n*16 + lr)*32 + lk*8];
    }
    #pragma unroll
    for (int m=0;m<4;m++)
      #pragma unroll
      for (int n=0;n<4;n++){
        acc1[m][n] = MFMA16(a[m], b1[n], acc1[m][n]);
        acc3[m][n] = MFMA16(a[m], b3[n], acc3[m][n]);
      }
  }
  #pragma unroll
  for (int m=0;m<4;m++){
    #pragma unroll
    for (int i=0;i<4;i++){
      const int r = wr*64 + m*16 + lk*4 + i;
      if (r < nv){
        const size_t rowbase = (size_t)(base + r) * NH;
        #pragma unroll
        for (int n=0;n<4;n++){
          float z  = acc1[m][n][i];
          float p3 = acc3[m][n][i];
          float hv = (z / (1.f + __expf(-z))) * p3;
          hbuf[rowbase + h0 + wc*64 + n*16 + lr] = f2bf(hv);
        }
      }
    }
  }
}

__global__ __launch_bounds__(256) void gemm2_k(
    const unsigned short* __restrict__ hbuf,
    const float* __restrict__ w2,
    float* __restrict__ out,
    const int* __restrict__ row_tok, const float* __restrict__ row_w,
    const int* __restrict__ counts, const int* __restrict__ offs)
{
  __shared__ unsigned short Al[128*32];
  __shared__ unsigned short Bl[128*32];
  const int e   = blockIdx.y >> 6;
  const int rb  = blockIdx.y & 63;
  const int cnt = counts[e];
  const int row0 = rb * 128;
  if (row0 >= cnt) return;
  const int nv   = min(128, cnt - row0);
  const int base = offs[e] + row0;
  const int d0   = blockIdx.x * 128;
  const int t  = threadIdx.x;
  const int ar0 = t >> 2;
  const int ac  = t & 3;
  const size_t asrc0 = (size_t)(base + min(ar0,      nv-1)) * NH + ac*8;
  const size_t asrc1 = (size_t)(base + min(ar0 + 64, nv-1)) * NH + ac*8;
  const int dg = t >> 5;
  const int hq = t & 31;
  const float* w2p = w2 + (size_t)e * NH * DIM + (size_t)(d0 + hq*4);
  const int wid = t >> 6, l = t & 63;
  const int wr = wid >> 1, wc = wid & 1;
  const int lr = l & 15,  lk = l >> 4;
  f32x4 acc[4][4];
  #pragma unroll
  for (int m=0;m<4;m++)
    #pragma unroll
    for (int n=0;n<4;n++) acc[m][n] = (f32x4)0.f;
  for (int kk=0; kk<NH/32; ++kk){
    const int k0 = kk*32;
    __syncthreads();
    *(uint4*)&Al[ar0*32 + ac*8]      = *(const uint4*)(hbuf + asrc0 + k0);
    *(uint4*)&Al[(ar0+64)*32 + ac*8] = *(const uint4*)(hbuf + asrc1 + k0);
    {
      const float4 f0 = *(const float4*)(w2p + (size_t)(k0 + dg*4 + 0)*DIM);
      const float4 f1 = *(const float4*)(w2p + (size_t)(k0 + dg*4 + 1)*DIM);
      const float4 f2 = *(const float4*)(w2p + (size_t)(k0 + dg*4 + 2)*DIM);
      const float4 f3 = *(const float4*)(w2p + (size_t)(k0 + dg*4 + 3)*DIM);
      const float* p0=(const float*)&f0; const float* p1=(const float*)&f1;
      const float* p2=(const float*)&f2; const float* p3=(const float*)&f3;
      #pragma unroll
      for (int j=0;j<4;j++){
        ushort4 pk = make_ushort4(f2bf(p0[j]), f2bf(p1[j]), f2bf(p2[j]), f2bf(p3[j]));
        *(ushort4*)&Bl[(hq*4+j)*32 + dg*4] = pk;
      }
    }
    __syncthreads();
    bf16x8 a[4], b[4];
    #pragma unroll
    for (int m=0;m<4;m++) a[m] = *(const bf16x8*)&Al[(wr*64 + m*16 + lr)*32 + lk*8];
    #pragma unroll
    for (int n=0;n<4;n++)  b[n] = *(const bf16x8*)&Bl[(wc*64 + n*16 + lr)*32 + lk*8];
    #pragma unroll
    for (int m=0;m<4;m++)
      #pragma unroll
      for (int n=0;n<4;n++)
        acc[m][n] = MFMA16(a[m], b[n], acc[m][n]);
  }
  #pragma unroll
  for (int m=0;m<4;m++){
    #pragma unroll
    for (int i=0;i<4;i++){
      const int r = wr*64 + m*16 + lk*4 + i;
      if (r < nv){
        const int flat = base + r;
        const int tok  = row_tok[flat];
        const float wgt = row_w[flat];
        float* orow = out + (size_t)tok * DIM + d0 + wc*64;
        #pragma unroll
        for (int n=0;n<4;n++)
          atomicAdd(&orow[n*16 + lr], acc[m][n][i] * wgt);
      }
    }
  }
}

// ---------------- launch ----------------

extern "C" void kernel_launch(void* const* d_in, const int* in_sizes, int n_in,
                              void* d_out, int out_size, void* d_ws, size_t ws_size,
                              hipStream_t stream) {
  (void)in_sizes; (void)n_in; (void)out_size;
  const float* x   = (const float*)d_in[0];
  const float* rw  = (const float*)d_in[1];
  const float* w1  = (const float*)d_in[2];
  const float* w2  = (const float*)d_in[3];
  const float* w3  = (const float*)d_in[4];
  float* out = (float*)d_out;
  char* ws = (char*)d_ws;

  const size_t SZ_XBF  = (size_t)T_TOK*DIM*2;
  const size_t SZ_HBUF = (size_t)NROWS*NH*2;
  const size_t SZ_WT   = (size_t)NE*NH*DIM*2;
  const size_t SZ_SMALL = (size_t)NROWS*4*2 + (size_t)T_TOK*2*4*2 + 3*64*4 + 4096;
  const size_t NEED_FAST = SZ_XBF + SZ_HBUF + 2*SZ_WT + SZ_SMALL;

  if (ws_size >= NEED_FAST) {
    size_t off = 0;
    unsigned short* xbf  = (unsigned short*)(ws + off); off += SZ_XBF;
    unsigned short* hbuf = (unsigned short*)(ws + off); off += SZ_HBUF;
    unsigned short* w1t  = (unsigned short*)(ws + off); off += SZ_WT;
    unsigned short* w3t  = (unsigned short*)(ws + off); off += SZ_WT;
    unsigned short* w2t  = w1t;  // w2t overlays w1t (dead after gemm1)
    int*   row_tok = (int*)  (ws + off); off += NROWS*4;
    float* row_w   = (float*)(ws + off); off += NROWS*4;
    int*   topk_e  = (int*)  (ws + off); off += T_TOK*2*4;
    float* topk_w  = (float*)(ws + off); off += T_TOK*2*4;
    int*   counts  = (int*)  (ws + off); off += 64;
    int*   offs    = (int*)  (ws + off); off += 64;
    int*   cursor  = (int*)  (ws + off); off += 64;

    init_k    <<<1, 64, 0, stream>>>(counts, cursor);
    zero_out_k<<<2048, 256, 0, stream>>>((float4*)out);
    cvt_k     <<<2048, 256, 0, stream>>>(x, xbf);
    router_k  <<<T_TOK, 64, 0, stream>>>(x, rw, topk_e, topk_w, counts);
    prefix_k  <<<1, 64, 0, stream>>>(counts, offs);
    scatter_k <<<(T_TOK+255)/256, 256, 0, stream>>>(topk_e, topk_w, offs, cursor, row_tok, row_w);
    transp2_k <<<dim3(DIM/64, NH/64, 2*NE), 256, 0, stream>>>(w1, w3, w1t, w3t);
    gemm1_8p  <<<dim3(64, 176), 512, 0, stream>>>(xbf, w1t, w3t, hbuf, row_tok, counts, offs);
    transp_k  <<<dim3(NH/64, DIM/64, NE), 256, 0, stream>>>(w2, w2t, NH, DIM);
    gemm2_8p  <<<dim3(64, 32), 512, 0, stream>>>(hbuf, w2t, out, row_tok, row_w, counts, offs);
  } else {
    size_t off = 0;
    unsigned short* xbf  = (unsigned short*)(ws + off); off += SZ_XBF;
    unsigned short* hbuf = (unsigned short*)(ws + off); off += SZ_HBUF;
    int*   row_tok = (int*)  (ws + off); off += NROWS*4;
    float* row_w   = (float*)(ws + off); off += NROWS*4;
    int*   topk_e  = (int*)  (ws + off); off += T_TOK*2*4;
    float* topk_w  = (float*)(ws + off); off += T_TOK*2*4;
    int*   counts  = (int*)  (ws + off); off += 64;
    int*   offs    = (int*)  (ws + off); off += 64;
    int*   cursor  = (int*)  (ws + off); off += 64;

    init_k    <<<1, 64, 0, stream>>>(counts, cursor);
    zero_out_k<<<2048, 256, 0, stream>>>((float4*)out);
    cvt_k     <<<2048, 256, 0, stream>>>(x, xbf);
    router_k  <<<T_TOK, 64, 0, stream>>>(x, rw, topk_e, topk_w, counts);
    prefix_k  <<<1, 64, 0, stream>>>(counts, offs);
    scatter_k <<<(T_TOK+255)/256, 256, 0, stream>>>(topk_e, topk_w, offs, cursor, row_tok, row_w);
    gemm1_k   <<<dim3(NH/128, NE*64), 256, 0, stream>>>(xbf, w1, w3, hbuf, row_tok, counts, offs);
    gemm2_k   <<<dim3(DIM/128, NE*64), 256, 0, stream>>>(hbuf, w2, out, row_tok, row_w, counts, offs);
  }
}